// Round 10
// baseline (267.068 us; speedup 1.0000x reference)
//
#include <hip/hip_runtime.h>
#include <hip/hip_bf16.h>

#define N_TOK 8192
#define DIN   1024
#define DOUT  1024
#define NE    8
#define KTOT  (NE * DIN)          // 8192
#define BM    256
#define BN    128
#define NKC   (KTOT / 32)         // 256 phases (k-chunk = 32)

typedef __attribute__((ext_vector_type(4))) float f32x4;
typedef __attribute__((ext_vector_type(8))) short short8;
typedef unsigned int u32;

__device__ __forceinline__ ushort f2bf(float f) {
    u32 u = __float_as_uint(f);
    u32 r = (u + 0x7fffu + ((u >> 16) & 1u)) >> 16;   // round-to-nearest-even
    return (ushort)r;
}

__device__ __forceinline__ void gload_lds16(const void* gp, void* lp) {
    __builtin_amdgcn_global_load_lds(
        (const __attribute__((address_space(1))) u32*)gp,
        (__attribute__((address_space(3))) u32*)lp, 16, 0, 0);
}

#define PH_BAR()  __builtin_amdgcn_s_barrier()
#define LGKM0()   asm volatile("s_waitcnt lgkmcnt(0)" ::: "memory")
#define LGKM4()   asm volatile("s_waitcnt lgkmcnt(4)" ::: "memory")
#define VMCNT6()  asm volatile("s_waitcnt vmcnt(6)" ::: "memory")
#define VMCNT4()  asm volatile("s_waitcnt vmcnt(4)" ::: "memory")
#define VMCNT0()  asm volatile("s_waitcnt vmcnt(0)" ::: "memory")
#define SBAR0()   __builtin_amdgcn_sched_barrier(0)

// ---------------- gating: softmax(x @ Wg + bg) -> g [N_TOK][NE] (f32) -----------
__global__ void gate_kernel(const float* __restrict__ x, const float* __restrict__ Wg,
                            const float* __restrict__ bg, float* __restrict__ g) {
    int w = threadIdx.x >> 6, lane = threadIdx.x & 63;
    int n = blockIdx.x * 4 + w;
    const float* xr = x + (size_t)n * DIN;
    float p[NE];
#pragma unroll
    for (int e = 0; e < NE; ++e) p[e] = 0.f;
    for (int i = lane; i < DIN; i += 64) {
        float xv = xr[i];
        const float* wr_ = Wg + i * NE;
#pragma unroll
        for (int e = 0; e < NE; ++e) p[e] = fmaf(xv, wr_[e], p[e]);
    }
#pragma unroll
    for (int off = 32; off > 0; off >>= 1) {
#pragma unroll
        for (int e = 0; e < NE; ++e) p[e] += __shfl_down(p[e], off);
    }
    if (lane == 0) {
        float l2[NE], m = -1e30f;
#pragma unroll
        for (int e = 0; e < NE; ++e) { l2[e] = p[e] + bg[e]; m = fmaxf(m, l2[e]); }
        float s = 0.f;
#pragma unroll
        for (int e = 0; e < NE; ++e) { l2[e] = expf(l2[e] - m); s += l2[e]; }
        float inv = 1.f / s;
#pragma unroll
        for (int e = 0; e < NE; ++e) g[n * NE + e] = l2[e] * inv;
    }
}

// ---------------- We [8192][1024] f32 -> B2 [256][1024][32] bf16 (kc-major) -----
// B2[kc][o][kk] = bf16(We[kc*32+kk][o]) : a wave's 4 B-frags become contiguous
// 1KB global reads (16 cols x 64B), fully coalesced.
__global__ void transpose_w2_kernel(const float* __restrict__ We, ushort* __restrict__ B2) {
    __shared__ float tile[64][65];
    int kb = blockIdx.x * 64, ob = blockIdx.y * 64;
    int t = threadIdx.x;
#pragma unroll
    for (int ph = 0; ph < 16; ++ph) {
        int idx = ph * 256 + t;
        int r = idx >> 6, c = idx & 63;
        tile[r][c] = We[(size_t)(kb + r) * DOUT + ob + c];
    }
    __syncthreads();
#pragma unroll
    for (int ph = 0; ph < 4; ++ph) {
        int widx = ph * 256 + t;          // 0..1023
        int o_loc = widx >> 4;            // 0..63
        int k_loc = (widx & 15) * 4;      // 0..60
        int kc = (kb + k_loc) >> 5;
        int kk = (kb + k_loc) & 31;
        ushort4 v;
        v.x = f2bf(tile[k_loc + 0][o_loc]);
        v.y = f2bf(tile[k_loc + 1][o_loc]);
        v.z = f2bf(tile[k_loc + 2][o_loc]);
        v.w = f2bf(tile[k_loc + 3][o_loc]);
        *(ushort4*)&B2[((size_t)kc * DOUT + ob + o_loc) * 32 + kk] = v;
    }
}

// ---------------- prescale: Ag[n][e*1024+i] = bf16(g[n][e] * x[n][i]) -----------
__global__ void prescale_kernel(const float* __restrict__ x, const float* __restrict__ g,
                                ushort* __restrict__ Ag) {
    int idx = blockIdx.x * 256 + threadIdx.x;   // n = idx>>7, c = idx&127
    int n = idx >> 7, c = idx & 127;
    float4 x0 = *(const float4*)&x[(size_t)n * DIN + c * 8];
    float4 x1 = *(const float4*)&x[(size_t)n * DIN + c * 8 + 4];
    float4 g0 = *(const float4*)&g[(size_t)n * NE + 0];
    float4 g1 = *(const float4*)&g[(size_t)n * NE + 4];
    float ge[NE] = {g0.x, g0.y, g0.z, g0.w, g1.x, g1.y, g1.z, g1.w};
#pragma unroll
    for (int e = 0; e < NE; ++e) {
        float s = ge[e];
        short8 v;
        v[0] = (short)f2bf(s * x0.x); v[1] = (short)f2bf(s * x0.y);
        v[2] = (short)f2bf(s * x0.z); v[3] = (short)f2bf(s * x0.w);
        v[4] = (short)f2bf(s * x1.x); v[5] = (short)f2bf(s * x1.y);
        v[6] = (short)f2bf(s * x1.z); v[7] = (short)f2bf(s * x1.w);
        *(short8*)&Ag[(size_t)n * KTOT + e * DIN + c * 8] = v;
    }
}

// ---------------- main GEMM: A via LDS ring-4, B coalesced global->reg ----------
// Phase k: {4 ds_read A-frags k+1} {stage A(k+3)} -> lgkm(4) -> SBAR0 ->
// 16 MFMA(fA[k&1], bReg[k&1]) -> issue B(k+2) (4 coalesced 1KB loads) ->
// vmcnt(6) -> barrier.  LDS pipe (A only, ~574cyc) < matrix pipe (620cyc).
__global__ __launch_bounds__(512, 2) void moe_gemm_ps2(
    const ushort* __restrict__ Ag,   // [8192][8192] bf16 (gate-prescaled fat A)
    const ushort* __restrict__ B2,   // [256][1024][32] bf16 (kc-major)
    const float*  __restrict__ g,    // [8192][8]
    const float*  __restrict__ be,   // [8][1024]
    float*        __restrict__ out)  // [8192][1024]
{
    __shared__ __align__(16) ushort Al[4][BM * 32];   // 64 KB ring (A only)
    __shared__ __align__(16) float  gLds[BM][NE];     //  8 KB

    int bid = blockIdx.x;
    int swz = (bid & 7) * 32 + (bid >> 3);      // XCD row-slab swizzle (proven)
    int colb = swz & 7;
    int rowb = swz >> 3;
    int brow = rowb * BM, bcol = colb * BN;

    int tid = threadIdx.x;
    int w = tid >> 6, lane = tid & 63;
    int wm = w >> 1, wn = w & 1;                 // 4x2 wave grid, 64x64 per wave
    int ro = lane & 15, gq = lane >> 4;
    int jrow = gq * 4;

    // gate probs -> LDS (for epilogue bias)
    float4 gv = ((const float4*)(g + (size_t)brow * NE))[tid];
    ((float4*)&gLds[0][0])[tid] = gv;

    // A fragment read offsets (T2 XOR-swizzled)
    int offA[4];
#pragma unroll
    for (int m = 0; m < 4; ++m) {
        int r = wm * 64 + m * 16 + ro;
        offA[m] = r * 32 + ((gq * 8) ^ ((r & 6) << 2));
    }
    // B per-lane global pointers: addr(kc) = ((kc*1024 + col)*32 + gq*8)*2B
    const ushort* bBase[4];
#pragma unroll
    for (int n = 0; n < 4; ++n) {
        int c = bcol + wn * 64 + n * 16 + ro;
        bBase[n] = B2 + (size_t)c * 32 + gq * 8;
    }

    auto stA = [&](int s, int K) {
#pragma unroll
        for (int L = 0; L < 2; ++L) {
            int chunk = L * 512 + tid;
            int row = chunk >> 2, slot = chunk & 3;
            int ks = (slot * 8) ^ ((row & 6) << 2);
            gload_lds16(Ag + (size_t)(brow + row) * KTOT + K * 32 + ks,
                        (char*)&Al[s][0] + (size_t)(chunk & ~63) * 16);
        }
    };

    f32x4 accP[4][4];
    short8 fA[2][4], bReg[2][4];   // literal-indexed only
#pragma unroll
    for (int m = 0; m < 4; ++m)
#pragma unroll
        for (int n = 0; n < 4; ++n) accP[m][n] = (f32x4){0.f, 0.f, 0.f, 0.f};

#define LD_FRAGS(SET, RBUF) do {                                              \
    const ushort* _As = &Al[RBUF][0];                                         \
    _Pragma("unroll") for (int _m = 0; _m < 4; ++_m)                          \
        fA[SET][_m] = *(const short8*)(_As + offA[_m]);                       \
} while (0)

#define ISSUE_B(SET, KC) do {                                                 \
    _Pragma("unroll") for (int _n = 0; _n < 4; ++_n)                          \
        bReg[SET][_n] = *(const short8*)(bBase[_n] + (size_t)(KC) * (DOUT * 32)); \
} while (0)

#define DO_MFMA(SET) do {                                                     \
    __builtin_amdgcn_s_setprio(1);                                            \
    _Pragma("unroll") for (int _m = 0; _m < 4; ++_m) {                        \
        accP[_m][0] = __builtin_amdgcn_mfma_f32_16x16x32_bf16(fA[SET][_m], bReg[SET][0], accP[_m][0], 0, 0, 0); \
        accP[_m][1] = __builtin_amdgcn_mfma_f32_16x16x32_bf16(fA[SET][_m], bReg[SET][1], accP[_m][1], 0, 0, 0); \
        accP[_m][2] = __builtin_amdgcn_mfma_f32_16x16x32_bf16(fA[SET][_m], bReg[SET][2], accP[_m][2], 0, 0, 0); \
        accP[_m][3] = __builtin_amdgcn_mfma_f32_16x16x32_bf16(fA[SET][_m], bReg[SET][3], accP[_m][3], 0, 0, 0); \
    }                                                                         \
    __builtin_amdgcn_s_setprio(0);                                            \
} while (0)

    // prologue: stage A rings 0..2; B(0)->set0, B(1)->set1; drain to B(1); frags 0
    stA(0, 0); stA(1, 1); stA(2, 2);
    ISSUE_B(0, 0); ISSUE_B(1, 1);
    VMCNT4();          // A0,A1,A2,B0 landed; B1 in flight
    PH_BAR();
    LD_FRAGS(0, 0);

    // main loop: phases 0..251 (63 iters x 4; ring/set indices literal)
    for (int it = 0; it < 63; ++it) {
        int k = it * 4;
        // phase k+0
        LD_FRAGS(1, 1); stA(3, k + 3);
        LGKM4(); SBAR0(); DO_MFMA(0);
        ISSUE_B(0, k + 2);
        VMCNT6(); PH_BAR();
        // phase k+1
        LD_FRAGS(0, 2); stA(0, k + 4);
        LGKM4(); SBAR0(); DO_MFMA(1);
        ISSUE_B(1, k + 3);
        VMCNT6(); PH_BAR();
        // phase k+2
        LD_FRAGS(1, 3); stA(1, k + 5);
        LGKM4(); SBAR0(); DO_MFMA(0);
        ISSUE_B(0, k + 4);
        VMCNT6(); PH_BAR();
        // phase k+3
        LD_FRAGS(0, 0); stA(2, k + 6);
        LGKM4(); SBAR0(); DO_MFMA(1);
        ISSUE_B(1, k + 5);
        VMCNT6(); PH_BAR();
    }

    // tail: phases 252..255 (drain)
    LD_FRAGS(1, 1); stA(3, 255);
    LGKM4(); SBAR0(); DO_MFMA(0);
    ISSUE_B(0, 254);
    VMCNT6(); PH_BAR();                       // phase 252
    LD_FRAGS(0, 2);
    LGKM4(); SBAR0(); DO_MFMA(1);
    ISSUE_B(1, 255);
    VMCNT4(); PH_BAR();                       // phase 253 (drain A255,B254)
    LD_FRAGS(1, 3);
    LGKM4(); SBAR0(); DO_MFMA(0);
    VMCNT0(); PH_BAR();                       // phase 254 (drain B255)
    LGKM0(); SBAR0(); DO_MFMA(1);             // phase 255

#undef LD_FRAGS
#undef ISSUE_B
#undef DO_MFMA

    // epilogue: out = accP + sum_e g_e * be_e   (single store, bias fused)
#pragma unroll
    for (int m = 0; m < 4; ++m) {
#pragma unroll
        for (int j = 0; j < 4; ++j) {
            int lrow = wm * 64 + m * 16 + jrow + j;
            int grow = brow + lrow;
            float g8[NE];
#pragma unroll
            for (int e = 0; e < NE; ++e) g8[e] = gLds[lrow][e];
#pragma unroll
            for (int n = 0; n < 4; ++n) {
                int col = bcol + wn * 64 + n * 16 + ro;
                float bias = 0.f;
#pragma unroll
                for (int e = 0; e < NE; ++e) bias = fmaf(g8[e], be[e * DOUT + col], bias);
                out[(size_t)grow * DOUT + col] = accP[m][n][j] + bias;
            }
        }
    }
}

extern "C" void kernel_launch(void* const* d_in, const int* in_sizes, int n_in,
                              void* d_out, int out_size, void* d_ws, size_t ws_size,
                              hipStream_t stream) {
    const float* x  = (const float*)d_in[0];
    const float* We = (const float*)d_in[1];
    const float* be = (const float*)d_in[2];
    const float* Wg = (const float*)d_in[3];
    const float* bg = (const float*)d_in[4];
    float* out = (float*)d_out;

    char* ws = (char*)d_ws;
    const size_t GB  = 256 * 1024;                        // gate probs
    const size_t BTB = (size_t)DOUT * KTOT * 2;           // 16 MB (B2)
    float*  gbuf = (float*)ws;
    ushort* B2   = (ushort*)(ws + GB);
    ushort* Ag   = (ushort*)(ws + GB + BTB);              // 128 MB

    gate_kernel<<<N_TOK / 4, 256, 0, stream>>>(x, Wg, bg, gbuf);
    transpose_w2_kernel<<<dim3(KTOT / 64, DOUT / 64), 256, 0, stream>>>(We, B2);
    prescale_kernel<<<(N_TOK * 128) / 256, 256, 0, stream>>>(x, gbuf, Ag);
    moe_gemm_ps2<<<(N_TOK / BM) * (DOUT / BN), 512, 0, stream>>>(Ag, B2, gbuf, be, out);
}

// Round 11
// 193.077 us; speedup vs baseline: 1.3832x; 1.3832x over previous
//
#include <hip/hip_runtime.h>
#include <hip/hip_bf16.h>

#define N_TOK 8192
#define DIN   1024
#define DOUT  1024
#define NE    8
#define KTOT  (NE * DIN)          // 8192
#define BM    128
#define BN    128
#define NKC   (KTOT / 32)         // 256 phases (k-chunk = 32)

typedef __attribute__((ext_vector_type(4))) float f32x4;
typedef __attribute__((ext_vector_type(8))) short short8;
typedef unsigned int u32;

__device__ __forceinline__ ushort f2bf(float f) {
    u32 u = __float_as_uint(f);
    u32 r = (u + 0x7fffu + ((u >> 16) & 1u)) >> 16;   // round-to-nearest-even
    return (ushort)r;
}

__device__ __forceinline__ void gload_lds16(const void* gp, void* lp) {
    __builtin_amdgcn_global_load_lds(
        (const __attribute__((address_space(1))) u32*)gp,
        (__attribute__((address_space(3))) u32*)lp, 16, 0, 0);
}

#define PH_BAR()  __builtin_amdgcn_s_barrier()
#define VMCNT4()  asm volatile("s_waitcnt vmcnt(4)" ::: "memory")
#define VMCNT0()  asm volatile("s_waitcnt vmcnt(0)" ::: "memory")

// ---------------- gating: softmax(x @ Wg + bg) -> g [N_TOK][NE] (f32) -----------
__global__ void gate_kernel(const float* __restrict__ x, const float* __restrict__ Wg,
                            const float* __restrict__ bg, float* __restrict__ g) {
    int w = threadIdx.x >> 6, lane = threadIdx.x & 63;
    int n = blockIdx.x * 4 + w;
    const float* xr = x + (size_t)n * DIN;
    float p[NE];
#pragma unroll
    for (int e = 0; e < NE; ++e) p[e] = 0.f;
    for (int i = lane; i < DIN; i += 64) {
        float xv = xr[i];
        const float* wr_ = Wg + i * NE;
#pragma unroll
        for (int e = 0; e < NE; ++e) p[e] = fmaf(xv, wr_[e], p[e]);
    }
#pragma unroll
    for (int off = 32; off > 0; off >>= 1) {
#pragma unroll
        for (int e = 0; e < NE; ++e) p[e] += __shfl_down(p[e], off);
    }
    if (lane == 0) {
        float l2[NE], m = -1e30f;
#pragma unroll
        for (int e = 0; e < NE; ++e) { l2[e] = p[e] + bg[e]; m = fmaxf(m, l2[e]); }
        float s = 0.f;
#pragma unroll
        for (int e = 0; e < NE; ++e) { l2[e] = expf(l2[e] - m); s += l2[e]; }
        float inv = 1.f / s;
#pragma unroll
        for (int e = 0; e < NE; ++e) g[n * NE + e] = l2[e] * inv;
    }
}

// ---------------- We [8192][1024] f32 -> B2 [256][1024][32] bf16 (kc-major) -----
__global__ void transpose_w2_kernel(const float* __restrict__ We, ushort* __restrict__ B2) {
    __shared__ float tile[64][65];
    int kb = blockIdx.x * 64, ob = blockIdx.y * 64;
    int t = threadIdx.x;
#pragma unroll
    for (int ph = 0; ph < 16; ++ph) {
        int idx = ph * 256 + t;
        int r = idx >> 6, c = idx & 63;
        tile[r][c] = We[(size_t)(kb + r) * DOUT + ob + c];
    }
    __syncthreads();
#pragma unroll
    for (int ph = 0; ph < 4; ++ph) {
        int widx = ph * 256 + t;          // 0..1023
        int o_loc = widx >> 4;            // 0..63
        int k_loc = (widx & 15) * 4;      // 0..60
        int kc = (kb + k_loc) >> 5;
        int kk = (kb + k_loc) & 31;
        ushort4 v;
        v.x = f2bf(tile[k_loc + 0][o_loc]);
        v.y = f2bf(tile[k_loc + 1][o_loc]);
        v.z = f2bf(tile[k_loc + 2][o_loc]);
        v.w = f2bf(tile[k_loc + 3][o_loc]);
        *(ushort4*)&B2[((size_t)kc * DOUT + ob + o_loc) * 32 + kk] = v;
    }
}

// ---------------- prescale: Ag[n][e*1024+i] = bf16(g[n][e] * x[n][i]) -----------
__global__ void prescale_kernel(const float* __restrict__ x, const float* __restrict__ g,
                                ushort* __restrict__ Ag) {
    int idx = blockIdx.x * 256 + threadIdx.x;   // n = idx>>7, c = idx&127
    int n = idx >> 7, c = idx & 127;
    float4 x0 = *(const float4*)&x[(size_t)n * DIN + c * 8];
    float4 x1 = *(const float4*)&x[(size_t)n * DIN + c * 8 + 4];
    float4 g0 = *(const float4*)&g[(size_t)n * NE + 0];
    float4 g1 = *(const float4*)&g[(size_t)n * NE + 4];
    float ge[NE] = {g0.x, g0.y, g0.z, g0.w, g1.x, g1.y, g1.z, g1.w};
#pragma unroll
    for (int e = 0; e < NE; ++e) {
        float s = ge[e];
        short8 v;
        v[0] = (short)f2bf(s * x0.x); v[1] = (short)f2bf(s * x0.y);
        v[2] = (short)f2bf(s * x0.z); v[3] = (short)f2bf(s * x0.w);
        v[4] = (short)f2bf(s * x1.x); v[5] = (short)f2bf(s * x1.y);
        v[6] = (short)f2bf(s * x1.z); v[7] = (short)f2bf(s * x1.w);
        *(short8*)&Ag[(size_t)n * KTOT + e * DIN + c * 8] = v;
    }
}

// ---------------- main GEMM: 128x128 tiles, 2 blocks/CU, ring-3 LDS --------------
// R9's proven phase (frag reads -> stage K+2 -> MFMA -> vmcnt(4) -> barrier), but
// grid 512 = 2 independent blocks per CU so LDS-read/DMA/MFMA bursts of one block
// overlap the other's (m114 cross-block co-scheduling). Bias fused in epilogue.
__global__ __launch_bounds__(256, 2) void moe_gemm_ps3(
    const ushort* __restrict__ Ag,   // [8192][8192] bf16 (gate-prescaled fat A)
    const ushort* __restrict__ B2,   // [256][1024][32] bf16 (kc-major)
    const float*  __restrict__ g,    // [8192][8]
    const float*  __restrict__ be,   // [8][1024]
    float*        __restrict__ out)  // [8192][1024]
{
    __shared__ __align__(16) ushort Al[3][BM * 32];   // 24 KB
    __shared__ __align__(16) ushort Bl[3][BN * 32];   // 24 KB
    __shared__ __align__(16) float  gLds[BM][NE];     //  4 KB

    int bid = blockIdx.x;
    // XCD row-slab swizzle (R1-proven at 512 blocks): bid&7 == XCD.
    int swz = (bid & 7) * 64 + (bid >> 3);
    int colb = swz & 7;
    int rowb = swz >> 3;
    int brow = rowb * BM, bcol = colb * BN;

    int tid = threadIdx.x;
    int w = tid >> 6, lane = tid & 63;
    int wm = w >> 1, wn = w & 1;                 // 2x2 wave grid, 64x64 per wave
    int ro = lane & 15, gq = lane >> 4;
    int jrow = gq * 4;

    // gate probs -> LDS (epilogue bias): 128 rows x 8 = 1024 floats = 256 float4
    ((float4*)&gLds[0][0])[tid] = ((const float4*)(g + (size_t)brow * NE))[tid];

    // fragment read offsets (T2 XOR-swizzled)
    int offA[4], offB[4];
#pragma unroll
    for (int m = 0; m < 4; ++m) {
        int r = wm * 64 + m * 16 + ro;
        offA[m] = r * 32 + ((gq * 8) ^ ((r & 6) << 2));
    }
#pragma unroll
    for (int n = 0; n < 4; ++n) {
        int c = wn * 64 + n * 16 + ro;
        offB[n] = c * 32 + ((gq * 8) ^ ((c & 6) << 2));
    }

    // staging group K: A 2 chunks/thread + B 2 chunks/thread (4 vmem ops/phase)
    auto stage = [&](int s, int K) {
#pragma unroll
        for (int L = 0; L < 2; ++L) {
            int c = L * 256 + tid;
            int row = c >> 2, slot = c & 3;
            int ks = (slot * 8) ^ ((row & 6) << 2);
            gload_lds16(Ag + (size_t)(brow + row) * KTOT + K * 32 + ks,
                        (char*)&Al[s][0] + (size_t)(c & ~63) * 16);
        }
#pragma unroll
        for (int L = 0; L < 2; ++L) {
            int c = L * 256 + tid;
            int col = c >> 2, slot = c & 3;
            int ks = (slot * 8) ^ ((col & 6) << 2);
            gload_lds16(B2 + ((size_t)K * DOUT + bcol + col) * 32 + ks,
                        (char*)&Bl[s][0] + (size_t)(c & ~63) * 16);
        }
    };

    f32x4 accP[4][4];
#pragma unroll
    for (int m = 0; m < 4; ++m)
#pragma unroll
        for (int n = 0; n < 4; ++n) accP[m][n] = (f32x4){0.f, 0.f, 0.f, 0.f};

// one phase: frag reads from BUF, stage K+2 into SBUF, 16 MFMA, counted wait, bar
#define PHASE(BUF, SBUF, KK, ISSUE, WAITN) do {                               \
    const ushort* _As = &Al[BUF][0];                                          \
    const ushort* _Bs = &Bl[BUF][0];                                          \
    short8 _a[4], _b[4];                                                      \
    _Pragma("unroll") for (int _m = 0; _m < 4; ++_m)                          \
        _a[_m] = *(const short8*)(_As + offA[_m]);                            \
    _Pragma("unroll") for (int _n = 0; _n < 4; ++_n)                          \
        _b[_n] = *(const short8*)(_Bs + offB[_n]);                            \
    if (ISSUE) stage(SBUF, (KK) + 2);                                         \
    __builtin_amdgcn_s_setprio(1);                                            \
    _Pragma("unroll") for (int _m = 0; _m < 4; ++_m) {                        \
        accP[_m][0] = __builtin_amdgcn_mfma_f32_16x16x32_bf16(_a[_m], _b[0], accP[_m][0], 0, 0, 0); \
        accP[_m][1] = __builtin_amdgcn_mfma_f32_16x16x32_bf16(_a[_m], _b[1], accP[_m][1], 0, 0, 0); \
        accP[_m][2] = __builtin_amdgcn_mfma_f32_16x16x32_bf16(_a[_m], _b[2], accP[_m][2], 0, 0, 0); \
        accP[_m][3] = __builtin_amdgcn_mfma_f32_16x16x32_bf16(_a[_m], _b[3], accP[_m][3], 0, 0, 0); \
    }                                                                         \
    __builtin_amdgcn_s_setprio(0);                                            \
    if ((WAITN) == 4) VMCNT4(); else if ((WAITN) == 0) VMCNT0();              \
    if ((WAITN) >= 0) PH_BAR();                                               \
} while (0)

    // prologue: stage groups 0,1; wait group 0 (leave 1 in flight); barrier
    stage(0, 0); stage(1, 1);
    VMCNT4();
    PH_BAR();

    // main loop: phases 0..251 (84 iters x 3; ring slot literal)
    for (int it = 0; it < 84; ++it) {
        int k = it * 3;
        PHASE(0, 2, k + 0, 1, 4);
        PHASE(1, 0, k + 1, 1, 4);
        PHASE(2, 1, k + 2, 1, 4);
    }
    // tail: 252 (issues 254), 253 (issues 255), 254 (drain), 255
    PHASE(0, 2, 252, 1, 4);
    PHASE(1, 0, 253, 1, 4);
    PHASE(2, 0, 254, 0, 0);
    PHASE(0, 0, 255, 0, -1);
#undef PHASE

    // epilogue: out = accP + sum_e g_e * be_e   (single store, bias fused)
#pragma unroll
    for (int m = 0; m < 4; ++m) {
#pragma unroll
        for (int j = 0; j < 4; ++j) {
            int lrow = wm * 64 + m * 16 + jrow + j;
            int grow = brow + lrow;
            float g8[NE];
#pragma unroll
            for (int e = 0; e < NE; ++e) g8[e] = gLds[lrow][e];
#pragma unroll
            for (int n = 0; n < 4; ++n) {
                int col = bcol + wn * 64 + n * 16 + ro;
                float bias = 0.f;
#pragma unroll
                for (int e = 0; e < NE; ++e) bias = fmaf(g8[e], be[e * DOUT + col], bias);
                out[(size_t)grow * DOUT + col] = accP[m][n][j] + bias;
            }
        }
    }
}

extern "C" void kernel_launch(void* const* d_in, const int* in_sizes, int n_in,
                              void* d_out, int out_size, void* d_ws, size_t ws_size,
                              hipStream_t stream) {
    const float* x  = (const float*)d_in[0];
    const float* We = (const float*)d_in[1];
    const float* be = (const float*)d_in[2];
    const float* Wg = (const float*)d_in[3];
    const float* bg = (const float*)d_in[4];
    float* out = (float*)d_out;

    char* ws = (char*)d_ws;
    const size_t GB  = 256 * 1024;                        // gate probs
    const size_t BTB = (size_t)DOUT * KTOT * 2;           // 16 MB (B2)
    float*  gbuf = (float*)ws;
    ushort* B2   = (ushort*)(ws + GB);
    ushort* Ag   = (ushort*)(ws + GB + BTB);              // 128 MB

    gate_kernel<<<N_TOK / 4, 256, 0, stream>>>(x, Wg, bg, gbuf);
    transpose_w2_kernel<<<dim3(KTOT / 64, DOUT / 64), 256, 0, stream>>>(We, B2);
    prescale_kernel<<<(N_TOK * 128) / 256, 256, 0, stream>>>(x, gbuf, Ag);
    moe_gemm_ps3<<<(N_TOK / BM) * (DOUT / BN), 256, 0, stream>>>(Ag, B2, gbuf, be, out);
}

// Round 12
// 192.915 us; speedup vs baseline: 1.3844x; 1.0008x over previous
//
#include <hip/hip_runtime.h>
#include <hip/hip_bf16.h>

#define N_TOK 8192
#define DIN   1024
#define DOUT  1024
#define NE    8
#define KTOT  (NE * DIN)          // 8192
#define BM    256
#define BN    128
#define NPH   128                 // phases: 128 local k-chunks (x2 ks-halves = 256)
#define SLOT  24576               // ushorts per ring slot: A0,A1 (8192 ea) + B0,B1 (4096 ea)

typedef __attribute__((ext_vector_type(4))) float f32x4;
typedef __attribute__((ext_vector_type(8))) short short8;
typedef unsigned int u32;

__device__ __forceinline__ ushort f2bf(float f) {
    u32 u = __float_as_uint(f);
    u32 r = (u + 0x7fffu + ((u >> 16) & 1u)) >> 16;   // round-to-nearest-even
    return (ushort)r;
}

__device__ __forceinline__ void gload_lds16(const void* gp, void* lp) {
    __builtin_amdgcn_global_load_lds(
        (const __attribute__((address_space(1))) u32*)gp,
        (__attribute__((address_space(3))) u32*)lp, 16, 0, 0);
}

#define PH_BAR()  __builtin_amdgcn_s_barrier()
#define VMCNT6()  asm volatile("s_waitcnt vmcnt(6)" ::: "memory")
#define VMCNT0()  asm volatile("s_waitcnt vmcnt(0)" ::: "memory")

// ---------------- gating: softmax(x @ Wg + bg) -> g [N_TOK][NE] (f32) -----------
__global__ void gate_kernel(const float* __restrict__ x, const float* __restrict__ Wg,
                            const float* __restrict__ bg, float* __restrict__ g) {
    int w = threadIdx.x >> 6, lane = threadIdx.x & 63;
    int n = blockIdx.x * 4 + w;
    const float* xr = x + (size_t)n * DIN;
    float p[NE];
#pragma unroll
    for (int e = 0; e < NE; ++e) p[e] = 0.f;
    for (int i = lane; i < DIN; i += 64) {
        float xv = xr[i];
        const float* wr_ = Wg + i * NE;
#pragma unroll
        for (int e = 0; e < NE; ++e) p[e] = fmaf(xv, wr_[e], p[e]);
    }
#pragma unroll
    for (int off = 32; off > 0; off >>= 1) {
#pragma unroll
        for (int e = 0; e < NE; ++e) p[e] += __shfl_down(p[e], off);
    }
    if (lane == 0) {
        float l2[NE], m = -1e30f;
#pragma unroll
        for (int e = 0; e < NE; ++e) { l2[e] = p[e] + bg[e]; m = fmaxf(m, l2[e]); }
        float s = 0.f;
#pragma unroll
        for (int e = 0; e < NE; ++e) { l2[e] = expf(l2[e] - m); s += l2[e]; }
        float inv = 1.f / s;
#pragma unroll
        for (int e = 0; e < NE; ++e) g[n * NE + e] = l2[e] * inv;
    }
}

// ---------------- We [8192][1024] f32 -> B2 [256][1024][32] bf16 (kc-major) -----
__global__ void transpose_w2_kernel(const float* __restrict__ We, ushort* __restrict__ B2) {
    __shared__ float tile[64][65];
    int kb = blockIdx.x * 64, ob = blockIdx.y * 64;
    int t = threadIdx.x;
#pragma unroll
    for (int ph = 0; ph < 16; ++ph) {
        int idx = ph * 256 + t;
        int r = idx >> 6, c = idx & 63;
        tile[r][c] = We[(size_t)(kb + r) * DOUT + ob + c];
    }
    __syncthreads();
#pragma unroll
    for (int ph = 0; ph < 4; ++ph) {
        int widx = ph * 256 + t;          // 0..1023
        int o_loc = widx >> 4;            // 0..63
        int k_loc = (widx & 15) * 4;      // 0..60
        int kc = (kb + k_loc) >> 5;
        int kk = (kb + k_loc) & 31;
        ushort4 v;
        v.x = f2bf(tile[k_loc + 0][o_loc]);
        v.y = f2bf(tile[k_loc + 1][o_loc]);
        v.z = f2bf(tile[k_loc + 2][o_loc]);
        v.w = f2bf(tile[k_loc + 3][o_loc]);
        *(ushort4*)&B2[((size_t)kc * DOUT + ob + o_loc) * 32 + kk] = v;
    }
}

// ---------------- prescale: Ag[n][e*1024+i] = bf16(g[n][e] * x[n][i]) -----------
__global__ void prescale_kernel(const float* __restrict__ x, const float* __restrict__ g,
                                ushort* __restrict__ Ag) {
    int idx = blockIdx.x * 256 + threadIdx.x;   // n = idx>>7, c = idx&127
    int n = idx >> 7, c = idx & 127;
    float4 x0 = *(const float4*)&x[(size_t)n * DIN + c * 8];
    float4 x1 = *(const float4*)&x[(size_t)n * DIN + c * 8 + 4];
    float4 g0 = *(const float4*)&g[(size_t)n * NE + 0];
    float4 g1 = *(const float4*)&g[(size_t)n * NE + 4];
    float ge[NE] = {g0.x, g0.y, g0.z, g0.w, g1.x, g1.y, g1.z, g1.w};
#pragma unroll
    for (int e = 0; e < NE; ++e) {
        float s = ge[e];
        short8 v;
        v[0] = (short)f2bf(s * x0.x); v[1] = (short)f2bf(s * x0.y);
        v[2] = (short)f2bf(s * x0.z); v[3] = (short)f2bf(s * x0.w);
        v[4] = (short)f2bf(s * x1.x); v[5] = (short)f2bf(s * x1.y);
        v[6] = (short)f2bf(s * x1.z); v[7] = (short)f2bf(s * x1.w);
        *(short8*)&Ag[(size_t)n * KTOT + e * DIN + c * 8] = v;
    }
}

// ---------------- main GEMM: 256x128 block, wave tile 128x64, in-block split-K ---
// 8 waves = 2wm x 2wn x 2ks. Each phase stages BOTH ks-halves' k-chunks
// (A0,A1 16KB ea + B0,B1 8KB ea = 48KB, 6 gloads/thread); each wave does 12
// ds_reads + 32 MFMA (6 reads/64x64-unit vs 8 before). Ring-3, vmcnt(6), stage
// K+2 ahead. Epilogue: ks=1 waves dump acc to LDS (reusing ring), ks=0 waves
// add + gate-weighted bias + store. No atomics, no fold.
__global__ __launch_bounds__(512, 2) void moe_gemm_sk(
    const ushort* __restrict__ Ag,   // [8192][8192] bf16 (gate-prescaled fat A)
    const ushort* __restrict__ B2,   // [256][1024][32] bf16 (kc-major)
    const float*  __restrict__ g,    // [8192][8]
    const float*  __restrict__ be,   // [8][1024]
    float*        __restrict__ out)  // [8192][1024]
{
    __shared__ __align__(16) ushort ring[3][SLOT];    // 144 KB
    __shared__ __align__(16) float  gLds[BM][NE];     //   8 KB

    int bid = blockIdx.x;
    int swz = (bid & 7) * 32 + (bid >> 3);      // XCD row-slab swizzle (proven)
    int colb = swz & 7;
    int rowb = swz >> 3;
    int brow = rowb * BM, bcol = colb * BN;

    int tid = threadIdx.x;
    int w = tid >> 6, lane = tid & 63;
    int wm = w >> 2, wn = (w >> 1) & 1, ks = w & 1;   // wave: rows, cols, K-half
    int ro = lane & 15, gq = lane >> 4;
    int jrow = gq * 4;

    // gate probs -> LDS (epilogue bias): 256 rows x 8 = 2048 floats = 512 float4
    ((float4*)&gLds[0][0])[tid] = ((const float4*)(g + (size_t)brow * NE))[tid];

    // fragment read offsets within this wave's A/B half (T2 XOR-swizzled)
    int aoff = ks * 8192;            // ushort offset of A{ks} in slot
    int boff = 16384 + ks * 4096;    // ushort offset of B{ks} in slot
    int offA[8], offB[4];
#pragma unroll
    for (int m = 0; m < 8; ++m) {
        int r = wm * 128 + m * 16 + ro;
        offA[m] = r * 32 + ((gq * 8) ^ ((r & 6) << 2));
    }
#pragma unroll
    for (int n = 0; n < 4; ++n) {
        int c = wn * 64 + n * 16 + ro;
        offB[n] = c * 32 + ((gq * 8) ^ ((c & 6) << 2));
    }

    // stage local phase p into slot s: A halves (2 gload x2) + B halves (1 x2)
    auto stage = [&](int s, int p) {
        char* base = (char*)&ring[s][0];
#pragma unroll
        for (int ksx = 0; ksx < 2; ++ksx) {
            int kc = ksx * NPH + p;
#pragma unroll
            for (int L = 0; L < 2; ++L) {
                int q = L * 512 + tid;
                int row = q >> 2, sl = q & 3;
                int ksz = (sl * 8) ^ ((row & 6) << 2);
                gload_lds16(Ag + (size_t)(brow + row) * KTOT + kc * 32 + ksz,
                            base + ksx * 16384 + (size_t)(q & ~63) * 16);
            }
        }
#pragma unroll
        for (int ksx = 0; ksx < 2; ++ksx) {
            int kc = ksx * NPH + p;
            int q = tid;
            int col = q >> 2, sl = q & 3;
            int ksz = (sl * 8) ^ ((col & 6) << 2);
            gload_lds16(B2 + ((size_t)kc * DOUT + bcol + col) * 32 + ksz,
                        base + 32768 + ksx * 8192 + (size_t)(q & ~63) * 16);
        }
    };

    f32x4 accP[8][4];
#pragma unroll
    for (int m = 0; m < 8; ++m)
#pragma unroll
        for (int n = 0; n < 4; ++n) accP[m][n] = (f32x4){0.f, 0.f, 0.f, 0.f};

#define PHASE(BUF, SBUF, KK, ISSUE, WAITN) do {                               \
    const ushort* _As = &ring[BUF][0] + aoff;                                 \
    const ushort* _Bs = &ring[BUF][0] + boff;                                 \
    short8 _a[8], _b[4];                                                      \
    _Pragma("unroll") for (int _m = 0; _m < 8; ++_m)                          \
        _a[_m] = *(const short8*)(_As + offA[_m]);                            \
    _Pragma("unroll") for (int _n = 0; _n < 4; ++_n)                          \
        _b[_n] = *(const short8*)(_Bs + offB[_n]);                            \
    if (ISSUE) stage(SBUF, (KK) + 2);                                         \
    __builtin_amdgcn_s_setprio(1);                                            \
    _Pragma("unroll") for (int _m = 0; _m < 8; ++_m) {                        \
        accP[_m][0] = __builtin_amdgcn_mfma_f32_16x16x32_bf16(_a[_m], _b[0], accP[_m][0], 0, 0, 0); \
        accP[_m][1] = __builtin_amdgcn_mfma_f32_16x16x32_bf16(_a[_m], _b[1], accP[_m][1], 0, 0, 0); \
        accP[_m][2] = __builtin_amdgcn_mfma_f32_16x16x32_bf16(_a[_m], _b[2], accP[_m][2], 0, 0, 0); \
        accP[_m][3] = __builtin_amdgcn_mfma_f32_16x16x32_bf16(_a[_m], _b[3], accP[_m][3], 0, 0, 0); \
    }                                                                         \
    __builtin_amdgcn_s_setprio(0);                                            \
    if ((WAITN) == 6) VMCNT6(); else if ((WAITN) == 0) VMCNT0();              \
    if ((WAITN) >= 0) PH_BAR();                                               \
} while (0)

    // prologue: stage phases 0,1; wait phase-0's 6 ops (leave 1's in flight)
    stage(0, 0); stage(1, 1);
    VMCNT6();
    PH_BAR();

    // main loop: phases 0..125 (42 iters x 3; ring slot literal)
    for (int it = 0; it < 42; ++it) {
        int k = it * 3;
        PHASE(0, 2, k + 0, 1, 6);
        PHASE(1, 0, k + 1, 1, 6);
        PHASE(2, 1, k + 2, 1, 6);
    }
    // tail: 126 (drain 127's ops), 127 (no wait)
    PHASE(0, 0, 126, 0, 0);
    PHASE(1, 0, 127, 0, -1);
#undef PHASE

    // ---- cross-ks reduce via LDS (reuse ring memory) + bias + store ----
    __syncthreads();                       // all MFMA reads of ring complete
    int pairIdx = wm * 2 + wn;             // 0..3
    float* red = (float*)&ring[0][0];      // 4 pairs x 128x64 f32 = 128 KB
    if (ks == 1) {
#pragma unroll
        for (int m = 0; m < 8; ++m)
#pragma unroll
            for (int j = 0; j < 4; ++j) {
                int lr = m * 16 + jrow + j;
#pragma unroll
                for (int n = 0; n < 4; ++n) {
                    int lc = n * 16 + ro;
                    red[pairIdx * 8192 + lr * 64 + lc] = accP[m][n][j];
                }
            }
    }
    __syncthreads();
    if (ks == 0) {
#pragma unroll
        for (int m = 0; m < 8; ++m) {
#pragma unroll
            for (int j = 0; j < 4; ++j) {
                int lr = m * 16 + jrow + j;
                int lrow = wm * 128 + lr;
                int grow = brow + lrow;
                float g8[NE];
#pragma unroll
                for (int e = 0; e < NE; ++e) g8[e] = gLds[lrow][e];
#pragma unroll
                for (int n = 0; n < 4; ++n) {
                    int lc = n * 16 + ro;
                    int col = bcol + wn * 64 + lc;
                    float bias = 0.f;
#pragma unroll
                    for (int e = 0; e < NE; ++e) bias = fmaf(g8[e], be[e * DOUT + col], bias);
                    out[(size_t)grow * DOUT + col] =
                        accP[m][n][j] + red[pairIdx * 8192 + lr * 64 + lc] + bias;
                }
            }
        }
    }
}

extern "C" void kernel_launch(void* const* d_in, const int* in_sizes, int n_in,
                              void* d_out, int out_size, void* d_ws, size_t ws_size,
                              hipStream_t stream) {
    const float* x  = (const float*)d_in[0];
    const float* We = (const float*)d_in[1];
    const float* be = (const float*)d_in[2];
    const float* Wg = (const float*)d_in[3];
    const float* bg = (const float*)d_in[4];
    float* out = (float*)d_out;

    char* ws = (char*)d_ws;
    const size_t GB  = 256 * 1024;                        // gate probs
    const size_t BTB = (size_t)DOUT * KTOT * 2;           // 16 MB (B2)
    float*  gbuf = (float*)ws;
    ushort* B2   = (ushort*)(ws + GB);
    ushort* Ag   = (ushort*)(ws + GB + BTB);              // 128 MB

    gate_kernel<<<N_TOK / 4, 256, 0, stream>>>(x, Wg, bg, gbuf);
    transpose_w2_kernel<<<dim3(KTOT / 64, DOUT / 64), 256, 0, stream>>>(We, B2);
    prescale_kernel<<<(N_TOK * 128) / 256, 256, 0, stream>>>(x, gbuf, Ag);
    moe_gemm_sk<<<(N_TOK / BM) * (DOUT / BN), 512, 0, stream>>>(Ag, B2, gbuf, be, out);
}